// Round 1
// baseline (1258.915 us; speedup 1.0000x reference)
//
#include <hip/hip_runtime.h>

#define HIDDEN 1024
#define FFN    4096
#define NEXP   8
#define NTOK   16384
#define CAP    16384
#define NPAIRS (2*NTOK)

#define BM 128
#define BN 128
#define BK 32

typedef _Float16 f16;
typedef _Float16 f16x8 __attribute__((ext_vector_type(8)));
typedef float    f32x4 __attribute__((ext_vector_type(4)));

typedef __attribute__((address_space(1))) const unsigned int gu32;
typedef __attribute__((address_space(3))) unsigned int lu32;

__device__ __forceinline__ void gll16(const void* g, void* l) {
  // async global->LDS, 16B per lane; LDS dest = wave-uniform base + lane*16
  __builtin_amdgcn_global_load_lds((gu32*)g, (lu32*)l, 16, 0, 0);
}

// ---------------- utility kernels ----------------

__global__ void k_sentinel(float* out) { if (threadIdx.x == 0) out[0] = -1e30f; }

__global__ void k_zero(float4* out, int n4) {
  int i = blockIdx.x * blockDim.x + threadIdx.x;
  int tot = gridDim.x * blockDim.x;
  for (int j = i; j < n4; j += tot) out[j] = float4{0.f, 0.f, 0.f, 0.f};
}

// fp32 -> fp16, 8 elems/thread
__global__ void k_cvt(const float* __restrict__ in, f16* __restrict__ out, int n8) {
  int i = blockIdx.x * blockDim.x + threadIdx.x;
  int tot = gridDim.x * blockDim.x;
  for (int j = i; j < n8; j += tot) {
    float4 a = ((const float4*)in)[2 * j];
    float4 b = ((const float4*)in)[2 * j + 1];
    f16x8 v = {(f16)a.x, (f16)a.y, (f16)a.z, (f16)a.w,
               (f16)b.x, (f16)b.y, (f16)b.z, (f16)b.w};
    ((f16x8*)out)[j] = v;
  }
}

// per-expert transpose+convert: in [R][C] f32 -> out [C][R] f16 (grid.z = expert)
__global__ void k_trans(const float* __restrict__ in, f16* __restrict__ out, int R, int C) {
  __shared__ float t[32][33];
  int z = blockIdx.z;
  const float* I = in + (size_t)z * R * C;
  f16* O = out + (size_t)z * R * C;
  int c0 = blockIdx.x * 32, r0 = blockIdx.y * 32;
  int tx = threadIdx.x & 31, ty = threadIdx.x >> 5;  // 32 x 8
  #pragma unroll
  for (int i = 0; i < 32; i += 8)
    t[ty + i][tx] = I[(size_t)(r0 + ty + i) * C + c0 + tx];
  __syncthreads();
  #pragma unroll
  for (int i = 0; i < 32; i += 8)
    O[(size_t)(c0 + ty + i) * R + r0 + tx] = (f16)t[tx][ty + i];
}

// gating: 1 wave per token; fp32 dot over HIDDEN for all 8 experts; top-2 + softmax
__global__ void k_gate(const float* __restrict__ x, const float* __restrict__ Wg,
                       const float* __restrict__ bg, int2* __restrict__ toke,
                       float2* __restrict__ tokw) {
  int wid = threadIdx.x >> 6, lane = threadIdx.x & 63;
  int tok = blockIdx.x * 4 + wid;
  const float* xr = x + (size_t)tok * HIDDEN;
  float s[8] = {0.f, 0.f, 0.f, 0.f, 0.f, 0.f, 0.f, 0.f};
  for (int j = lane; j < HIDDEN; j += 64) {
    float xv = xr[j];
    const float4* wr = (const float4*)(Wg + j * 8);
    float4 wa = wr[0], wb = wr[1];
    s[0] += xv * wa.x; s[1] += xv * wa.y; s[2] += xv * wa.z; s[3] += xv * wa.w;
    s[4] += xv * wb.x; s[5] += xv * wb.y; s[6] += xv * wb.z; s[7] += xv * wb.w;
  }
  #pragma unroll
  for (int off = 32; off > 0; off >>= 1) {
    #pragma unroll
    for (int e = 0; e < 8; ++e) s[e] += __shfl_down(s[e], off);
  }
  if (lane == 0) {
    float best = -1e30f, second = -1e30f;
    int bi = 0, si = 0;
    #pragma unroll
    for (int e = 0; e < 8; ++e) {
      float v = s[e] + bg[e];
      if (v > best)        { second = best; si = bi; best = v; bi = e; }
      else if (v > second) { second = v; si = e; }
    }
    float p = expf(second - best);
    float inv = 1.0f / (1.0f + p);
    toke[tok] = make_int2(bi, si);
    tokw[tok] = make_float2(inv, p * inv);
  }
}

// build per-expert compact pair lists (one block per expert; LDS-atomic cursor)
__global__ void k_build(const int2* __restrict__ toke, const float2* __restrict__ tokw,
                        int* __restrict__ pair_tok, float* __restrict__ pair_w,
                        int* __restrict__ counts) {
  int e = blockIdx.x;
  __shared__ int cursor;
  if (threadIdx.x == 0) cursor = 0;
  __syncthreads();
  for (int i = threadIdx.x; i < NTOK; i += blockDim.x) {
    int2 ee = toke[i];
    float2 ww = tokw[i];
    if (ee.x == e) { int p = atomicAdd(&cursor, 1); pair_tok[e * CAP + p] = i; pair_w[e * CAP + p] = ww.x; }
    if (ee.y == e) { int p = atomicAdd(&cursor, 1); pair_tok[e * CAP + p] = i; pair_w[e * CAP + p] = ww.y; }
  }
  __syncthreads();
  if (threadIdx.x == 0) counts[e] = cursor;
}

// ---------------- GEMM1: h = relu(Xg @ W1e + b1e), fp16 MFMA ----------------
// A: gathered x rows (fp16 [NTOK][HIDDEN]); B: w1t [E][FFN][HIDDEN] (pre-transposed)
__global__ __launch_bounds__(256, 2) void k_ffn1(
    const f16* __restrict__ xh, const f16* __restrict__ w1t,
    const float* __restrict__ b1, f16* __restrict__ hbuf,
    const int* __restrict__ pair_tok, const int* __restrict__ counts) {
  const int e = blockIdx.z;
  const int cnt = counts[e];
  const int m0 = blockIdx.y * BM;
  if (m0 >= cnt) return;
  const int n0 = blockIdx.x * BN;
  int hbase = 0;
  #pragma unroll
  for (int j = 0; j < NEXP; ++j) hbase += (j < e) ? counts[j] : 0;

  __shared__ f16 As[BM][BK];
  __shared__ f16 Bs[BN][BK];
  const int tid = threadIdx.x;
  const int lane = tid & 63, wid = tid >> 6;
  const int wm = (wid & 1) * 64, wn = (wid >> 1) * 64;

  // staging: wave w covers rows [w*32, w*32+32) in 2 calls of 16 rows
  const int sr = lane >> 2, kc = lane & 3;
  const int maxr = cnt - 1 - m0;
  const int* toks = pair_tok + e * CAP + m0;
  const int ra0 = wid * 32 + sr, ra1 = ra0 + 16;
  const f16* aptr0 = xh + (size_t)toks[min(ra0, maxr)] * HIDDEN + kc * 8;
  const f16* aptr1 = xh + (size_t)toks[min(ra1, maxr)] * HIDDEN + kc * 8;
  const f16* bbase = w1t + (size_t)e * FFN * HIDDEN;
  const f16* bptr0 = bbase + (size_t)(n0 + ra0) * HIDDEN + kc * 8;
  const f16* bptr1 = bbase + (size_t)(n0 + ra1) * HIDDEN + kc * 8;

  f32x4 zero4 = {0.f, 0.f, 0.f, 0.f};
  f32x4 acc[4][4];
  #pragma unroll
  for (int m = 0; m < 4; ++m)
    #pragma unroll
    for (int n = 0; n < 4; ++n) acc[m][n] = zero4;

  const int cl = lane & 15, rg = lane >> 4;
  for (int k0 = 0; k0 < HIDDEN; k0 += BK) {
    gll16(aptr0 + k0, &As[wid * 32][0]);
    gll16(aptr1 + k0, &As[wid * 32 + 16][0]);
    gll16(bptr0 + k0, &Bs[wid * 32][0]);
    gll16(bptr1 + k0, &Bs[wid * 32 + 16][0]);
    __syncthreads();
    f16x8 af[4], bf[4];
    #pragma unroll
    for (int m = 0; m < 4; ++m) af[m] = *(const f16x8*)&As[wm + m * 16 + cl][rg * 8];
    #pragma unroll
    for (int n = 0; n < 4; ++n) bf[n] = *(const f16x8*)&Bs[wn + n * 16 + cl][rg * 8];
    #pragma unroll
    for (int m = 0; m < 4; ++m)
      #pragma unroll
      for (int n = 0; n < 4; ++n)
        acc[m][n] = __builtin_amdgcn_mfma_f32_16x16x32_f16(af[m], bf[n], acc[m][n], 0, 0, 0);
    __syncthreads();
  }

  float bias[4];
  #pragma unroll
  for (int n = 0; n < 4; ++n) bias[n] = b1[(size_t)e * FFN + n0 + wn + n * 16 + cl];
  #pragma unroll
  for (int m = 0; m < 4; ++m) {
    #pragma unroll
    for (int i = 0; i < 4; ++i) {
      int rl = wm + m * 16 + rg * 4 + i;
      if (m0 + rl < cnt) {
        f16* hp = hbuf + (size_t)(hbase + m0 + rl) * FFN + n0 + wn + cl;
        #pragma unroll
        for (int n = 0; n < 4; ++n) {
          float v = acc[m][n][i] + bias[n];
          hp[n * 16] = (f16)fmaxf(v, 0.0f);
        }
      }
    }
  }
}

// ---------------- GEMM2: out += cw * (h @ W2e + b2e) ----------------
// A: h rows (fp16 [NPAIRS][FFN]); B: w2t [E][HIDDEN][FFN] (pre-transposed)
__global__ __launch_bounds__(256, 2) void k_ffn2(
    const f16* __restrict__ hbuf, const f16* __restrict__ w2t,
    const float* __restrict__ b2, float* __restrict__ out,
    const int* __restrict__ pair_tok, const float* __restrict__ pair_w,
    const int* __restrict__ counts) {
  const int e = blockIdx.z;
  const int cnt = counts[e];
  const int m0 = blockIdx.y * BM;
  if (m0 >= cnt) return;
  const int n0 = blockIdx.x * BN;
  int hbase = 0;
  #pragma unroll
  for (int j = 0; j < NEXP; ++j) hbase += (j < e) ? counts[j] : 0;

  __shared__ f16 As[BM][BK];
  __shared__ f16 Bs[BN][BK];
  const int tid = threadIdx.x;
  const int lane = tid & 63, wid = tid >> 6;
  const int wm = (wid & 1) * 64, wn = (wid >> 1) * 64;

  const int sr = lane >> 2, kc = lane & 3;
  const int maxr = cnt - 1 - m0;
  const int ra0 = wid * 32 + sr, ra1 = ra0 + 16;
  const f16* aptr0 = hbuf + (size_t)(hbase + m0 + min(ra0, maxr)) * FFN + kc * 8;
  const f16* aptr1 = hbuf + (size_t)(hbase + m0 + min(ra1, maxr)) * FFN + kc * 8;
  const f16* bbase = w2t + (size_t)e * HIDDEN * FFN;
  const f16* bptr0 = bbase + (size_t)(n0 + ra0) * FFN + kc * 8;
  const f16* bptr1 = bbase + (size_t)(n0 + ra1) * FFN + kc * 8;

  f32x4 zero4 = {0.f, 0.f, 0.f, 0.f};
  f32x4 acc[4][4];
  #pragma unroll
  for (int m = 0; m < 4; ++m)
    #pragma unroll
    for (int n = 0; n < 4; ++n) acc[m][n] = zero4;

  const int cl = lane & 15, rg = lane >> 4;
  for (int k0 = 0; k0 < FFN; k0 += BK) {
    gll16(aptr0 + k0, &As[wid * 32][0]);
    gll16(aptr1 + k0, &As[wid * 32 + 16][0]);
    gll16(bptr0 + k0, &Bs[wid * 32][0]);
    gll16(bptr1 + k0, &Bs[wid * 32 + 16][0]);
    __syncthreads();
    f16x8 af[4], bf[4];
    #pragma unroll
    for (int m = 0; m < 4; ++m) af[m] = *(const f16x8*)&As[wm + m * 16 + cl][rg * 8];
    #pragma unroll
    for (int n = 0; n < 4; ++n) bf[n] = *(const f16x8*)&Bs[wn + n * 16 + cl][rg * 8];
    #pragma unroll
    for (int m = 0; m < 4; ++m)
      #pragma unroll
      for (int n = 0; n < 4; ++n)
        acc[m][n] = __builtin_amdgcn_mfma_f32_16x16x32_f16(af[m], bf[n], acc[m][n], 0, 0, 0);
    __syncthreads();
  }

  float bias[4];
  #pragma unroll
  for (int n = 0; n < 4; ++n) bias[n] = b2[(size_t)e * HIDDEN + n0 + wn + n * 16 + cl];
  #pragma unroll
  for (int m = 0; m < 4; ++m) {
    #pragma unroll
    for (int i = 0; i < 4; ++i) {
      int rl = wm + m * 16 + rg * 4 + i;
      if (m0 + rl < cnt) {
        int p = e * CAP + m0 + rl;
        int tok = pair_tok[p];
        float w = pair_w[p];
        float* op = out + (size_t)tok * HIDDEN + n0 + wn + cl;
        #pragma unroll
        for (int n = 0; n < 4; ++n)
          atomicAdd(&op[n * 16], (acc[m][n][i] + bias[n]) * w);
      }
    }
  }
}

// ---------------- host ----------------

static constexpr size_t alignup(size_t v) { return (v + 255) & ~size_t(255); }

extern "C" void kernel_launch(void* const* d_in, const int* in_sizes, int n_in,
                              void* d_out, int out_size, void* d_ws, size_t ws_size,
                              hipStream_t stream) {
  const float* x  = (const float*)d_in[0];
  const float* Wg = (const float*)d_in[1];
  const float* bg = (const float*)d_in[2];
  const float* W1 = (const float*)d_in[3];
  const float* b1 = (const float*)d_in[4];
  const float* W2 = (const float*)d_in[5];
  const float* b2 = (const float*)d_in[6];
  float* out = (float*)d_out;

  // workspace layout
  size_t off = 0;
  char* ws = (char*)d_ws;
  auto take = [&](size_t bytes) { void* p = ws + off; off += alignup(bytes); return p; };
  f16*    xh       = (f16*)take((size_t)NTOK * HIDDEN * 2);
  f16*    w1t      = (f16*)take((size_t)NEXP * FFN * HIDDEN * 2);
  f16*    w2t      = (f16*)take((size_t)NEXP * HIDDEN * FFN * 2);
  f16*    hbuf     = (f16*)take((size_t)NPAIRS * FFN * 2);
  int*    pair_tok = (int*)take((size_t)NEXP * CAP * 4);
  float*  pair_w   = (float*)take((size_t)NEXP * CAP * 4);
  int2*   toke     = (int2*)take((size_t)NTOK * 8);
  float2* tokw     = (float2*)take((size_t)NTOK * 8);
  int*    counts   = (int*)take(64);

  if (off > ws_size) {  // workspace too small -> emit sentinel so it's diagnosable
    k_sentinel<<<1, 64, 0, stream>>>(out);
    return;
  }

  k_zero<<<2048, 256, 0, stream>>>((float4*)out, NTOK * HIDDEN / 4);
  k_cvt<<<2048, 256, 0, stream>>>(x, xh, NTOK * HIDDEN / 8);
  k_trans<<<dim3(FFN / 32, HIDDEN / 32, NEXP), 256, 0, stream>>>(W1, w1t, HIDDEN, FFN);
  k_trans<<<dim3(HIDDEN / 32, FFN / 32, NEXP), 256, 0, stream>>>(W2, w2t, FFN, HIDDEN);
  k_gate<<<NTOK / 4, 256, 0, stream>>>(x, Wg, bg, toke, tokw);
  k_build<<<NEXP, 256, 0, stream>>>(toke, tokw, pair_tok, pair_w, counts);
  k_ffn1<<<dim3(FFN / BN, CAP / BM, NEXP), 256, 0, stream>>>(xh, w1t, b1, hbuf, pair_tok, counts);
  k_ffn2<<<dim3(HIDDEN / BN, CAP / BM, NEXP), 256, 0, stream>>>(hbuf, w2t, b2, out, pair_tok, pair_w, counts);
}